// Round 2
// baseline (3434.388 us; speedup 1.0000x reference)
//
#include <hip/hip_runtime.h>
#include <math.h>

namespace {
constexpr int DIN   = 36;
constexpr int DOUT  = 34;
constexpr int BATCH = 8;
constexpr int TOTAL = BATCH * DOUT * DOUT * DOUT;   // 314432 outputs
constexpr int ROW   = DIN;

// block tile: (d,e,f) = (4,8,8); grid = 8 batches x 9 x 5 x 5 = 1800 blocks
constexpr int TD = 4, TE = 8, TF = 8;
constexpr int NBD = 9, NBE = 5, NBF = 5;            // ceil(34/4), ceil(34/8), ceil(34/8)
constexpr int BLOCKS_PER_B = NBD * NBE * NBF;       // 225
constexpr int NBLOCKS = BATCH * BLOCKS_PER_B;       // 1800 (divisible by 8 XCDs)
}

__global__ __launch_bounds__(256, 8)
void lasl_kernel(const float* __restrict__ xr, const float* __restrict__ xi,
                 const float* __restrict__ wr, const float* __restrict__ wi,
                 const float* __restrict__ br, const float* __restrict__ bi,
                 const float* __restrict__ hw, const float* __restrict__ hb,
                 float* __restrict__ out)
{
    __shared__ float s_wr[81], s_wi[81], s_hw[DOUT], s_scal[3];
    const int t = threadIdx.x;
    if (t < 81)                       { s_wr[t] = wr[t]; s_wi[t] = wi[t]; }
    else if (t >= 96 && t < 96+DOUT)  { s_hw[t-96] = hw[t-96]; }
    else if (t == 160)                { s_scal[0] = br[0]; s_scal[1] = bi[0]; s_scal[2] = hb[0]; }
    __syncthreads();

    // XCD-aware bijective swizzle: 1800 = 8 * 225, each XCD owns one batch.
    const int bid = blockIdx.x;
    const int swz = (bid & 7) * BLOCKS_PER_B + (bid >> 3);

    int rem = swz;
    const int bf = rem % NBF;  rem /= NBF;
    const int be = rem % NBE;  rem /= NBE;
    const int bd = rem % NBD;  rem /= NBD;
    const int b  = rem;                       // 0..7

    const int f = bf * TF + (t & 7);
    const int e = be * TE + ((t >> 3) & 7);
    const int d = bd * TD + (t >> 6);
    if (d >= DOUT || e >= DOUT || f >= DOUT) return;

    const float c_br = s_scal[0];
    const float c_bi = s_scal[1];
    float h          = s_scal[2];

    const size_t idx3 = (((size_t)b * DIN + d) * DIN + e) * DIN + f;

    #pragma unroll
    for (int half = 0; half < 2; ++half)
    {
        const int w0 = half * 17;
        float yr[17], yi[17];
        #pragma unroll
        for (int w = 0; w < 17; ++w) { yr[w] = c_br; yi[w] = c_bi; }

        #pragma unroll 1
        for (int i = 0; i < 3; ++i)
        #pragma unroll 1
        for (int j = 0; j < 3; ++j)
        #pragma unroll 1
        for (int k = 0; k < 3; ++k)
        {
            const size_t roff = (idx3 + (size_t)(i*(DIN*DIN) + j*DIN + k)) * ROW
                              + (size_t)half * 16;
            float4 bufr[5], bufi[5];
            const float4* pr = reinterpret_cast<const float4*>(xr + roff);
            const float4* pi = reinterpret_cast<const float4*>(xi + roff);
            #pragma unroll
            for (int q = 0; q < 5; ++q) { bufr[q] = pr[q]; bufi[q] = pi[q]; }
            const float* rr = reinterpret_cast<const float*>(bufr);
            const float* ri = reinterpret_cast<const float*>(bufi);

            const int tap = ((i*3 + j)*3 + k)*3;
            #pragma unroll
            for (int l = 0; l < 3; ++l)
            {
                const float wrl = s_wr[tap + l];
                const float wil = s_wi[tap + l];
                #pragma unroll
                for (int w = 0; w < 17; ++w)
                {
                    const int idx = w + l + half;
                    yr[w] = fmaf(ri[idx], -wil, fmaf(rr[idx], wrl, yr[w]));
                    yi[w] = fmaf(ri[idx],  wrl, fmaf(rr[idx], wil, yi[w]));
                }
            }
        }

        #pragma unroll
        for (int w = 0; w < 17; ++w)
        {
            float a = fmaxf(yr[w], 0.0f);
            float c = fmaxf(yi[w], 0.0f);
            float m = sqrtf(fmaf(a, a, fmaf(c, c, 1e-12f)));
            h = fmaf(m, s_hw[w0 + w], h);
        }
    }

    out[(((size_t)b * DOUT + d) * DOUT + e) * DOUT + f] = 1.0f / (1.0f + __expf(-h));
}

extern "C" void kernel_launch(void* const* d_in, const int* in_sizes, int n_in,
                              void* d_out, int out_size, void* d_ws, size_t ws_size,
                              hipStream_t stream)
{
    const float* xr = (const float*)d_in[0];
    const float* xi = (const float*)d_in[1];
    const float* wr = (const float*)d_in[2];
    const float* wi = (const float*)d_in[3];
    const float* br = (const float*)d_in[4];
    const float* bi = (const float*)d_in[5];
    const float* hw = (const float*)d_in[6];
    const float* hb = (const float*)d_in[7];
    float* out = (float*)d_out;

    lasl_kernel<<<NBLOCKS, 256, 0, stream>>>(xr, xi, wr, wi, br, bi, hw, hb, out);
}

// Round 3
// 959.103 us; speedup vs baseline: 3.5808x; 3.5808x over previous
//
#include <hip/hip_runtime.h>
#include <math.h>

namespace {
constexpr int DIN   = 36;
constexpr int DOUT  = 34;
constexpr int BATCH = 8;

// block tile: (d,e,f) = (4,4,8) outputs; each output uses a LANE PAIR (w-halves)
// -> 128 outputs * 2 lanes = 256 threads/block
constexpr int TD = 4, TE = 4, TF = 8;
constexpr int NBD = 9, NBE = 9, NBF = 5;             // ceil(34/4), ceil(34/4), ceil(34/8)
constexpr int BLOCKS_PER_B = NBD * NBE * NBF;        // 405
constexpr int NBLOCKS = BATCH * BLOCKS_PER_B;        // 3240 = 8 XCDs x 405
}

__global__ __launch_bounds__(256, 4)
void lasl_kernel(const float* __restrict__ xr, const float* __restrict__ xi,
                 const float* __restrict__ wr, const float* __restrict__ wi,
                 const float* __restrict__ br, const float* __restrict__ bi,
                 const float* __restrict__ hw, const float* __restrict__ hb,
                 float* __restrict__ out)
{
    __shared__ float s_wr[81], s_wi[81], s_hw[DOUT], s_scal[3];
    const int t = threadIdx.x;
    if (t < 81)                       { s_wr[t] = wr[t]; s_wi[t] = wi[t]; }
    else if (t >= 96 && t < 96+DOUT)  { s_hw[t-96] = hw[t-96]; }
    else if (t == 160)                { s_scal[0] = br[0]; s_scal[1] = bi[0]; s_scal[2] = hb[0]; }
    __syncthreads();

    // Bijective XCD swizzle: 3240 = 8 * 405; XCD x owns batch x entirely.
    const int bid = blockIdx.x;
    const int swz = (bid & 7) * BLOCKS_PER_B + (bid >> 3);
    const int b   = swz / BLOCKS_PER_B;              // == bid & 7
    int rem       = swz % BLOCKS_PER_B;
    const int bd  = rem / (NBE * NBF);
    rem          %= NBE * NBF;
    const int be  = rem / NBF;
    const int bf  = rem % NBF;

    // lane pair: bit0 = w-half; (f,e,d) from higher bits (f fastest for coalescing)
    const int half = t & 1;
    const int f = bf * TF + ((t >> 1) & 7);
    const int e = be * TE + ((t >> 4) & 3);
    const int d = bd * TD + (t >> 6);
    if (d >= DOUT || e >= DOUT || f >= DOUT) return;   // pair-uniform, shfl-safe

    const float c_br = s_scal[0];
    const float c_bi = s_scal[1];

    float yr[17], yi[17];
    #pragma unroll
    for (int w = 0; w < 17; ++w) { yr[w] = c_br; yi[w] = c_bi; }

    // byte-aligned segment: this lane reads floats [half*16, half*16+20) of each row
    const size_t rowbase = ((((size_t)b * DIN + d) * DIN + e) * DIN + f) * DIN
                         + (size_t)half * 16;

    #pragma unroll 1
    for (int i = 0; i < 3; ++i)
    #pragma unroll 1
    for (int j = 0; j < 3; ++j)
    #pragma unroll 1
    for (int k = 0; k < 3; ++k)
    {
        const size_t off = rowbase + (size_t)(i*(DIN*DIN) + j*DIN + k) * DIN;
        const int tap = ((i*3 + j)*3 + k)*3;

        float4 buf[5];
        const float* rr = reinterpret_cast<const float*>(buf);

        // ---- pass 1: real input (contributes +wr to yr, +wi to yi)
        {
            const float4* pr = reinterpret_cast<const float4*>(xr + off);
            #pragma unroll
            for (int q = 0; q < 5; ++q) buf[q] = pr[q];
            #pragma unroll
            for (int l = 0; l < 3; ++l)
            {
                const float wrl = s_wr[tap + l];
                const float wil = s_wi[tap + l];
                #pragma unroll
                for (int w = 0; w < 17; ++w)
                {
                    const float v = rr[w + l + half];
                    yr[w] = fmaf(v, wrl, yr[w]);
                    yi[w] = fmaf(v, wil, yi[w]);
                }
            }
        }
        // ---- pass 2: imag input (contributes -wi to yr, +wr to yi)
        {
            const float4* pi = reinterpret_cast<const float4*>(xi + off);
            #pragma unroll
            for (int q = 0; q < 5; ++q) buf[q] = pi[q];
            #pragma unroll
            for (int l = 0; l < 3; ++l)
            {
                const float wrl = s_wr[tap + l];
                const float wil = s_wi[tap + l];
                #pragma unroll
                for (int w = 0; w < 17; ++w)
                {
                    const float v = rr[w + l + half];
                    yr[w] = fmaf(v, -wil, yr[w]);
                    yi[w] = fmaf(v,  wrl, yi[w]);
                }
            }
        }
    }

    // CReLU -> modulus -> head partial over this lane's 17 w's
    float h = half ? 0.0f : s_scal[2];        // hb added exactly once per pair
    const int w0 = half * 17;
    #pragma unroll
    for (int w = 0; w < 17; ++w)
    {
        float a = fmaxf(yr[w], 0.0f);
        float c = fmaxf(yi[w], 0.0f);
        float m = sqrtf(fmaf(a, a, fmaf(c, c, 1e-12f)));
        h = fmaf(m, s_hw[w0 + w], h);
    }

    h += __shfl_xor(h, 1);                    // combine the two w-halves
    if (!half)
        out[(((size_t)b * DOUT + d) * DOUT + e) * DOUT + f] = 1.0f / (1.0f + __expf(-h));
}

extern "C" void kernel_launch(void* const* d_in, const int* in_sizes, int n_in,
                              void* d_out, int out_size, void* d_ws, size_t ws_size,
                              hipStream_t stream)
{
    const float* xr = (const float*)d_in[0];
    const float* xi = (const float*)d_in[1];
    const float* wr = (const float*)d_in[2];
    const float* wi = (const float*)d_in[3];
    const float* br = (const float*)d_in[4];
    const float* bi = (const float*)d_in[5];
    const float* hw = (const float*)d_in[6];
    const float* hb = (const float*)d_in[7];
    float* out = (float*)d_out;

    lasl_kernel<<<NBLOCKS, 256, 0, stream>>>(xr, xi, wr, wi, br, bi, hw, hb, out);
}

// Round 4
// 502.758 us; speedup vs baseline: 6.8311x; 1.9077x over previous
//
#include <hip/hip_runtime.h>
#include <math.h>

namespace {
constexpr int DIN   = 36;
constexpr int DOUT  = 34;
constexpr int BATCH = 8;
constexpr int ROW   = DIN;

// block tile: (d,e,f) = (4,8,8) -> 256 outputs, one per thread
constexpr int TD = 4, TE = 8, TF = 8;
constexpr int NBD = 9, NBE = 5, NBF = 5;            // ceil(34/4), ceil(34/8), ceil(34/8)
constexpr int BLOCKS_PER_B = NBD * NBE * NBF;       // 225
constexpr int NBLOCKS = BATCH * BLOCKS_PER_B;       // 1800 = 8 XCDs x 225
}

__global__ __launch_bounds__(256, 4)
void lasl_kernel(const float* __restrict__ xr, const float* __restrict__ xi,
                 const float* __restrict__ wr, const float* __restrict__ wi,
                 const float* __restrict__ br, const float* __restrict__ bi,
                 const float* __restrict__ hw, const float* __restrict__ hb,
                 float* __restrict__ out)
{
    __shared__ float s_wr[81], s_wi[81], s_hw[DOUT], s_scal[3];
    const int t = threadIdx.x;
    if (t < 81)                       { s_wr[t] = wr[t]; s_wi[t] = wi[t]; }
    else if (t >= 96 && t < 96+DOUT)  { s_hw[t-96] = hw[t-96]; }
    else if (t == 160)                { s_scal[0] = br[0]; s_scal[1] = bi[0]; s_scal[2] = hb[0]; }
    __syncthreads();

    // Bijective XCD swizzle: 1800 = 8 * 225; XCD x owns batch x entirely.
    const int bid = blockIdx.x;
    const int b   = bid & 7;
    int rem       = bid >> 3;                        // 0..224, f-major within batch
    const int bd  = rem / (NBE * NBF);
    rem          %= NBE * NBF;
    const int be  = rem / NBF;
    const int bf  = rem % NBF;

    const int f = bf * TF + (t & 7);
    const int e = be * TE + ((t >> 3) & 7);
    const int d = bd * TD + (t >> 6);
    if (d >= DOUT || e >= DOUT || f >= DOUT) return;

    const float c_br = s_scal[0];
    const float c_bi = s_scal[1];
    float h          = s_scal[2];

    const size_t idx3 = (((size_t)b * DIN + d) * DIN + e) * DIN + f;

    // Two w-halves, COMPILE-TIME unrolled (keeps all buffer indices constant).
    #pragma unroll
    for (int half = 0; half < 2; ++half)
    {
        const int w0 = half * 17;
        float yr[17], yi[17];
        #pragma unroll
        for (int w = 0; w < 17; ++w) { yr[w] = c_br; yi[w] = c_bi; }

        #pragma unroll 1
        for (int i = 0; i < 3; ++i)
        #pragma unroll 1
        for (int j = 0; j < 3; ++j)
        #pragma unroll 1
        for (int k = 0; k < 3; ++k)
        {
            const size_t roff = (idx3 + (size_t)(i*(DIN*DIN) + j*DIN + k)) * ROW
                              + (size_t)half * 16;
            float4 bufr[5], bufi[5];
            const float4* pr = reinterpret_cast<const float4*>(xr + roff);
            const float4* pi = reinterpret_cast<const float4*>(xi + roff);
            #pragma unroll
            for (int q = 0; q < 5; ++q) { bufr[q] = pr[q]; bufi[q] = pi[q]; }
            const float* rr = reinterpret_cast<const float*>(bufr);
            const float* ri = reinterpret_cast<const float*>(bufi);

            const int tap = ((i*3 + j)*3 + k)*3;
            #pragma unroll
            for (int l = 0; l < 3; ++l)
            {
                const float wrl = s_wr[tap + l];
                const float wil = s_wi[tap + l];
                #pragma unroll
                for (int w = 0; w < 17; ++w)
                {
                    const int idx = w + l + half;   // compile-time constant
                    yr[w] = fmaf(ri[idx], -wil, fmaf(rr[idx], wrl, yr[w]));
                    yi[w] = fmaf(ri[idx],  wrl, fmaf(rr[idx], wil, yi[w]));
                }
            }
        }

        #pragma unroll
        for (int w = 0; w < 17; ++w)
        {
            float a = fmaxf(yr[w], 0.0f);
            float c = fmaxf(yi[w], 0.0f);
            float m = sqrtf(fmaf(a, a, fmaf(c, c, 1e-12f)));
            h = fmaf(m, s_hw[w0 + w], h);
        }
    }

    out[(((size_t)b * DOUT + d) * DOUT + e) * DOUT + f] = 1.0f / (1.0f + __expf(-h));
}

extern "C" void kernel_launch(void* const* d_in, const int* in_sizes, int n_in,
                              void* d_out, int out_size, void* d_ws, size_t ws_size,
                              hipStream_t stream)
{
    const float* xr = (const float*)d_in[0];
    const float* xi = (const float*)d_in[1];
    const float* wr = (const float*)d_in[2];
    const float* wi = (const float*)d_in[3];
    const float* br = (const float*)d_in[4];
    const float* bi = (const float*)d_in[5];
    const float* hw = (const float*)d_in[6];
    const float* hb = (const float*)d_in[7];
    float* out = (float*)d_out;

    lasl_kernel<<<NBLOCKS, 256, 0, stream>>>(xr, xi, wr, wi, br, bi, hw, hb, out);
}